// Round 16
// baseline (226.346 us; speedup 1.0000x reference)
//
#include <hip/hip_runtime.h>
#include <math.h>

// VectorQuantizer: x (32768,64) f32, codebook (8192,64) f32, start/end/use_sk ints.
// Outputs concat: x_q_st (2097152 f32) | loss (1 f32) | indices (32768 as f32 values).
//
// R25 = R24 pass1 (raw f16 minima records; epilogue-lite) + rescue rewritten to
// kill the straggler tail R24's counters exposed (block lifetime mean 21.5us vs
// max 71.5us: tokens statically bound to waves + serial un-pipelined evals).
//  vq_rescue changes:
//   1. BLOCK-LEVEL JOB QUEUE: phase A pushes (token,chunk) jobs to one shared LDS
//      list (capacity 4096 = exact structural max: each (token,chunk) pushed at
//      most once -> NO overflow path); waves pop TWO jobs per round via LDS
//      atomic -> work balances across the 4 waves.
//   2. TWO CHUNKS PER ROUND, 1 LANE/CODE: lanes 0-31 evaluate job A's 32 codes,
//      lanes 32-63 job B's. Each lane computes the full CANONICAL R1 pairwise-8
//      dot (t0..t7, i ascending, separate mul+add == the original bit-exact
//      form; the old 2-lane j-split was derived from it by IEEE add
//      commutativity). Lex-min reduces within each 32-lane half (shfl_xor offs
//      16..1 stay in-half); one LDS CAS-min per half into per-token bp.
//   3. Epilogue: wave wv owns tokens 4wv..4wv+3 (= one legacy partial group),
//      EXACT legacy loss tree (6x shfl_down, (s0+s1)+(s2+s3), partial[tok>>2]).
//  vq_pass1 (byte-identical to R24): 32x32x16 MFMA filter, 128 tok x 1024 codes,
//      raw per-chunk f16 minima -> token-major 64B records via minL LDS.
// Exactness: thr = min over ALL 256 f16 chunk minima + WINDOW (no truncation).
// Ref argmin k*: mv(chunk of k*) <= g_bf(k*) <= gmin + 2*err_bf + sc_max
// (1.6e-4 + 1e-6 < W=3e-4) -> its chunk always survives -> every in-range code
// of surviving chunks evaluated exactly (canonical R1 arithmetic) -> lex-min
// over a superset containing the reference argmin == reference. Out-of-range
// chunks record +inf; out-of-range codes filtered by k in [s,e).
// DO NOT change the exact-path arithmetic: inter-code d gaps are ~1 ulp of d.

#define N_E    8192
#define EDIM   64
#define NTOK   32768
#define NELEM  (NTOK * EDIM)
#define CSZ    32                  // chunk size
#define WINDOW 3e-4f
#define TTOK   128                 // pass-1 tokens per block
#define TCODE  1024                // pass-1 codes per block (eighth)
#define SROW   72                  // Cs stride (ushorts; 36 dwords == 4 mod 8)
#define TOKB   16                  // rescue tokens per block
#define JCAP   4096                // job-list capacity (= exact structural max 16*256)

typedef __attribute__((ext_vector_type(8)))  short          short8;
typedef __attribute__((ext_vector_type(8)))  unsigned short ushort8v;
typedef __attribute__((ext_vector_type(16))) float          f32x16;

__device__ __forceinline__ unsigned short f2bf(float f) {   // RTNE f32->bf16 bits
  unsigned int u = __float_as_uint(f);
  return (unsigned short)((u + 0x7FFFu + ((u >> 16) & 1u)) >> 16);
}
__device__ __forceinline__ unsigned short f2h(float f) {
  union { _Float16 h; unsigned short u; } cv; cv.h = (_Float16)f; return cv.u;
}
__device__ __forceinline__ float h2f(unsigned short b) {
  union { _Float16 h; unsigned short u; } cv; cv.u = b; return (float)cv.h;
}
__device__ __forceinline__ float max16(const f32x16 a) {   // v_max3-fusible chain
  float m = fmaxf(fmaxf(a[0], a[1]), a[2]);
  m = fmaxf(fmaxf(m, a[3]),  a[4]);
  m = fmaxf(fmaxf(m, a[5]),  a[6]);
  m = fmaxf(fmaxf(m, a[7]),  a[8]);
  m = fmaxf(fmaxf(m, a[9]),  a[10]);
  m = fmaxf(fmaxf(m, a[11]), a[12]);
  m = fmaxf(fmaxf(m, a[13]), a[14]);
  return fmaxf(m, a[15]);
}
// sx = np.sum(x*x) pairwise-8 replica (reads a 64-f32 row via float4*)
__device__ __forceinline__ float sx_of(const float4* xl4) {
#pragma clang fp contract(off)
  float a0=0,a1=0,a2=0,a3=0,a4=0,a5=0,a6=0,a7=0;
#pragma unroll
  for (int i = 0; i < 8; ++i) {
    float4 pA = xl4[2*i], pB = xl4[2*i+1];
    a0 += pA.x * pA.x; a1 += pA.y * pA.y; a2 += pA.z * pA.z; a3 += pA.w * pA.w;
    a4 += pB.x * pB.x; a5 += pB.y * pB.y; a6 += pB.z * pB.z; a7 += pB.w * pB.w;
  }
  return ((a0+a1) + (a2+a3)) + ((a4+a5) + (a6+a7));
}

// ---------------- sc (exact pairwise-8) + cb -> bf16 rows (K=64) --------------------
__global__ __launch_bounds__(256) void vq_sc(const float* __restrict__ cb,
                                             float* __restrict__ sc,
                                             unsigned short* __restrict__ cbf) {
#pragma clang fp contract(off)
  int r = blockIdx.x * 256 + threadIdx.x;
  const float4* c4 = (const float4*)(cb + (size_t)r * EDIM);
  float sval = sx_of(c4);
  sc[r] = sval;
  unsigned short* dst = cbf + (size_t)r * EDIM;
#pragma unroll
  for (int h = 0; h < 8; ++h) {
    float4 fA = c4[2*h], fB = c4[2*h+1];
    ushort8v o = {f2bf(fA.x), f2bf(fA.y), f2bf(fA.z), f2bf(fA.w),
                  f2bf(fB.x), f2bf(fB.y), f2bf(fB.z), f2bf(fB.w)};
    *(ushort8v*)&dst[h * 8] = o;
  }
}

// ---------------- pass 1: MFMA filter -> raw per-chunk f16 minima records -----------
// (byte-identical to R24)
__global__ __launch_bounds__(256, 4) void vq_pass1(
    const float* __restrict__ x, const unsigned short* __restrict__ cbf,
    unsigned int* __restrict__ cand,
    const int* __restrict__ p_start, const int* __restrict__ p_end) {
  __shared__ unsigned short Cs[128 * SROW];     // 18432 B
  __shared__ unsigned minL[128 * 17];           // 8704 B (u16 idx: tl*34 + cidL)
  int tid = threadIdx.x;
  int tb = blockIdx.x;    // token split [0,256)
  int cbk = blockIdx.y;   // code split  [0,8)  (the "eighth")
  int s = *p_start, e = *p_end;
  const bool allfull = (cbk * TCODE >= s) && (cbk * TCODE + TCODE <= e);

  int lane = tid & 63, wv = tid >> 6;
  int half = lane >> 5, ln = lane & 31;
  int tokbase = wv * 32;                        // wave owns 32 tokens

  const ushort8v* cg0 = (const ushort8v*)(cbf + (size_t)cbk * TCODE * EDIM);
#pragma unroll
  for (int p = 0; p < 4; ++p) {
    int idx = tid + p * 256;
    int row = idx >> 3, h = idx & 7;
    *(ushort8v*)&Cs[row * SROW + h * 8] = cg0[idx];
  }

  short8 bfr[4];
  {
    const float* xrow =
        x + (size_t)(tb * TTOK + tokbase + ln) * EDIM + half * 8;
#pragma unroll
    for (int ks = 0; ks < 4; ++ks) {
      float4 fA = *(const float4*)(xrow + ks * 16);
      float4 fB = *(const float4*)(xrow + ks * 16 + 4);
      short8 v = {(short)f2bf(fA.x), (short)f2bf(fA.y), (short)f2bf(fA.z),
                  (short)f2bf(fA.w), (short)f2bf(fB.x), (short)f2bf(fB.y),
                  (short)f2bf(fB.z), (short)f2bf(fB.w)};
      bfr[ks] = v;
    }
  }
  __syncthreads();

  unsigned short* minL16 = (unsigned short*)minL;

  for (int nb = 0; nb < 8; ++nb) {
    ushort8v creg[4];
    if (nb < 7) {                                // prefetch next tile into registers
      const ushort8v* cg =
          (const ushort8v*)(cbf + ((size_t)cbk * TCODE + (nb + 1) * 128) * EDIM);
#pragma unroll
      for (int p = 0; p < 4; ++p) creg[p] = cg[tid + p * 256];
    }
#pragma unroll
    for (int cp = 0; cp < 2; ++cp) {
      f32x16 acc[2];
#pragma unroll
      for (int c2 = 0; c2 < 2; ++c2) acc[c2] = (f32x16)0.0f;
#pragma unroll
      for (int ks = 0; ks < 4; ++ks)
#pragma unroll
        for (int c2 = 0; c2 < 2; ++c2) {
          int ct = cp * 2 + c2;
          short8 a = *(const short8*)&Cs[(ct*32 + ln) * SROW + ks*16 + half*8];
          acc[c2] = __builtin_amdgcn_mfma_f32_32x32x16_bf16(a, bfr[ks],
                                                            acc[c2], 0, 0, 0);
        }
#pragma unroll
      for (int c2 = 0; c2 < 2; ++c2) {
        int cidL = nb * 4 + cp * 2 + c2;         // local chunk id (0..31)
        float v;
        if (allfull) {                           // kernel-uniform fast path
          v = max16(acc[c2]);
        } else {
          int c0 = cbk * TCODE + cidL * 32;
          bool full = (c0 >= s) && (c0 + 32 <= e);
          if (full) {
            v = max16(acc[c2]);
          } else {
            v = -INFINITY;                       // fully-out chunk -> +inf record
#pragma unroll
            for (int r = 0; r < 16; ++r) {
              int code = c0 + (r & 3) + 8 * (r >> 2) + 4 * half;
              if (code >= s && code < e) v = fmaxf(v, acc[c2][r]);
            }
          }
        }
        v = fmaxf(v, __shfl_xor(v, 32, 64));     // chunk max (pair-merge, uniform)
        if (!half)                               // one u16 store per (token,chunk)
          minL16[(tokbase + ln) * 34 + cidL] = f2h(-2.0f * v);
      }
    }
    __syncthreads();                             // all Cs reads done
    if (nb < 7) {
#pragma unroll
      for (int p = 0; p < 4; ++p) {
        int idx = tid + p * 256;
        int row = idx >> 3, h = idx & 7;
        *(ushort8v*)&Cs[row * SROW + h * 8] = creg[p];
      }
    }
    __syncthreads();                             // Cs + minL writes visible
  }

  // ---- flush: 512 uint4 = 128 records x 4 full-line parts (coalesced) ----
#pragma unroll
  for (int p = 0; p < 2; ++p) {
    int idx = tid + p * 256;                     // [0, 512)
    int tl = idx >> 2, part = idx & 3;           // tl in [0, 128)
    const unsigned* src = minL + tl * 17 + part * 4;
    uint4 v; v.x = src[0]; v.y = src[1]; v.z = src[2]; v.w = src[3];
    *(uint4*)(cand + (((size_t)(tb * TTOK + tl)) * 8 + cbk) * 16 + part * 4) = v;
  }
}

// ---------------- pass 2: job-queue rescue (2 chunks/round) + fused epilogue --------
__global__ __launch_bounds__(256) void vq_rescue(
    const float* __restrict__ x, const float* __restrict__ cb,
    const float* __restrict__ sc, const unsigned int* __restrict__ cand,
    float* __restrict__ out_xq, float* __restrict__ out_idx,
    float* __restrict__ partial,
    const int* __restrict__ p_start, const int* __restrict__ p_end) {
#pragma clang fp contract(off)
  __shared__ float xsh[TOKB][64];                 // 4 KB staged x rows
  __shared__ float sxs[TOKB];                     // exact sx per token
  __shared__ unsigned short jobs[JCAP];           // 8 KB (tl<<8 | chunk)
  __shared__ unsigned long long bp[TOKB];         // per-token lex-min packs
  __shared__ int jcnt, jpos;
  int tid  = threadIdx.x;
  int wv   = tid >> 6;
  int lane = tid & 63;
  int blk  = blockIdx.x;
  int s = *p_start, e = *p_end;

  if (tid < TOKB) bp[tid] = ~0ull;
  if (tid == 0) { jcnt = 0; jpos = 0; }
  __syncthreads();

  // ---- phase A (split across waves; one barrier) --------------------------------
  if (tid < 128) {
    // waves 0-1: one (token, eighth) unit each; record = ONE contiguous 64B read
    int tl = tid >> 3, q = tid & 7;
    int gtok = blk * TOKB + tl;
    const uint4* rp = (const uint4*)(cand + ((size_t)gtok * 8 + q) * 16);
    uint4 A0 = rp[0], A1 = rp[1], A2 = rp[2], A3 = rp[3];
    unsigned rw[16] = {A0.x, A0.y, A0.z, A0.w, A1.x, A1.y, A1.z, A1.w,
                       A2.x, A2.y, A2.z, A2.w, A3.x, A3.y, A3.z, A3.w};
    float m = INFINITY;
#pragma unroll
    for (int j = 0; j < 16; ++j) {
      unsigned u = rw[j];
      m = fminf(m, fminf(h2f((unsigned short)(u & 0xFFFFu)),
                         h2f((unsigned short)(u >> 16))));
    }
    m = fminf(m, __shfl_xor(m, 1, 64));          // combine the token's 8 eighths
    m = fminf(m, __shfl_xor(m, 2, 64));
    m = fminf(m, __shfl_xor(m, 4, 64));
    float thr = m + WINDOW;                      // global window threshold
#pragma unroll
    for (int j = 0; j < 16; ++j) {
      unsigned u = rw[j];
      if (h2f((unsigned short)(u & 0xFFFFu)) <= thr) {
        int i = atomicAdd(&jcnt, 1);             // capacity exact: no guard needed
        jobs[i] = (unsigned short)((tl << 8) | (q * 32 + 2 * j));
      }
      if (h2f((unsigned short)(u >> 16)) <= thr) {
        int i = atomicAdd(&jcnt, 1);
        jobs[i] = (unsigned short)((tl << 8) | (q * 32 + 2 * j + 1));
      }
    }
  } else if (tid < 192) {
    // wave 2: stage x rows (coalesced: 4 threads x 64B per 256B row)
    int t = tid - 128;                           // 0..63
#pragma unroll
    for (int p = 0; p < 4; ++p) {
      int idx = t + p * 64;                      // 0..255 float4 units
      int tl = idx >> 4, seg = idx & 15;
      *(float4*)&xsh[tl][seg * 4] =
          ((const float4*)(x + (size_t)(blk * TOKB + tl) * EDIM))[seg];
    }
  } else if (tid < 192 + TOKB) {
    // wave 3: exact sx per token (serial pairwise-8 replica, from global/L2)
    int tl = tid - 192;
    sxs[tl] = sx_of((const float4*)(x + (size_t)(blk * TOKB + tl) * EDIM));
  }
  __syncthreads();

  // ---- phase B: waves pop TWO jobs per round; 1 lane/code (canonical R1 eval) ----
  int n = jcnt;
  int ln32 = lane & 31, half32 = lane >> 5;
  for (;;) {
    int idx = 0;
    if (lane == 0) idx = atomicAdd(&jpos, 2);
    idx = __shfl(idx, 0, 64);
    if (idx >= n) break;
    unsigned jA = jobs[idx];
    bool haveB = (idx + 1 < n);
    unsigned jB = haveB ? jobs[idx + 1] : jA;    // duplicate A: safe addresses
    unsigned jv = half32 ? jB : jA;
    bool act = half32 ? haveB : true;
    int tlh = (int)(jv >> 8) & 15;
    int ch  = (int)(jv & 255u);
    int k   = ch * CSZ + ln32;
    // canonical R1 pairwise-8 dot: t0..t7, i ascending, separate mul+add
    const float4* c4 = (const float4*)(cb + (size_t)k * EDIM);
    const float4* xl4 = (const float4*)xsh[tlh];
    float sck = sc[k];
    float sxh = sxs[tlh];
    float t0=0,t1=0,t2=0,t3=0,t4=0,t5=0,t6=0,t7=0;
#pragma unroll
    for (int i = 0; i < 8; ++i) {                // elements 8i..8i+7, i ascending
      float4 cA = c4[2*i], cB = c4[2*i+1];
      float4 pA = xl4[2*i], pB = xl4[2*i+1];
      t0 += cA.x * pA.x; t1 += cA.y * pA.y; t2 += cA.z * pA.z; t3 += cA.w * pA.w;
      t4 += cB.x * pB.x; t5 += cB.y * pB.y; t6 += cB.z * pB.z; t7 += cB.w * pB.w;
    }
    float tt = ((t0+t1) + (t2+t3)) + ((t4+t5) + (t6+t7));
    unsigned long long pk = ~0ull;
    if (act && k >= s && k < e) {
      float d = (sxh + sck) - 2.0f * tt;
      unsigned db = __float_as_uint(d);
      unsigned en = db ^ ((unsigned)((int)db >> 31) | 0x80000000u);
      pk = ((unsigned long long)en << 32) | (unsigned)k;
    }
    // lex-min within each 32-lane half (offsets < 32 stay in-half)
#pragma unroll
    for (int off = 16; off >= 1; off >>= 1) {
      unsigned long long o = __shfl_xor(pk, off, 64);
      if (o < pk) pk = o;
    }
    if (ln32 == 0 && pk != ~0ull) {              // one CAS-min per half
      unsigned long long cur = bp[tlh];
      while (pk < cur) {
        unsigned long long pr = atomicCAS(&bp[tlh], cur, pk);
        if (pr == cur) break;
        cur = pr;
      }
    }
  }
  __syncthreads();

  // ---- epilogue: wave wv owns tokens 4wv..4wv+3 (= one legacy partial group) ----
  float sg[4];
#pragma unroll
  for (int ti = 0; ti < 4; ++ti) {
    int tl = wv * 4 + ti;
    int gtok = blk * TOKB + tl;
    int bidx = (int)(unsigned)(bp[tl] & 0xFFFFFFFFull) & (N_E - 1);
    float xx = xsh[tl][lane];
    float qv = cb[(size_t)bidx * EDIM + lane];
    float diff = qv - xx;                              // fl(x_q - x)
    out_xq[(size_t)gtok * EDIM + lane] = xx + diff;    // fl(x + fl(x_q - x))
    if (lane == 0) out_idx[gtok] = (float)bidx;
    float l = diff * diff;
#pragma unroll
    for (int off = 32; off >= 1; off >>= 1) l += __shfl_down(l, off, 64);
    sg[ti] = l;                                  // legacy per-token tree
  }
  if (lane == 0)
    partial[blk * 4 + wv] = (sg[0] + sg[1]) + (sg[2] + sg[3]);
}

// ---------------- final loss reduction ----------------------------------------------
__global__ __launch_bounds__(256) void vq_loss(const float* __restrict__ partial,
                                               float* __restrict__ out_loss) {
  int tid = threadIdx.x;
  float s = 0.0f;
  for (int i = tid; i < NTOK / 4; i += 256) s += partial[i];
#pragma unroll
  for (int off = 32; off >= 1; off >>= 1) s += __shfl_down(s, off, 64);
  __shared__ float sdata[4];
  if ((tid & 63) == 0) sdata[tid >> 6] = s;
  __syncthreads();
  if (tid == 0) {
    float total = (sdata[0] + sdata[1]) + (sdata[2] + sdata[3]);
    float m = total * (1.0f / (float)NELEM);
    out_loss[0] = m + 0.25f * m;
  }
}

// ---------------- launch -------------------------------------------------------------
extern "C" void kernel_launch(void* const* d_in, const int* in_sizes, int n_in,
                              void* d_out, int out_size, void* d_ws, size_t ws_size,
                              hipStream_t stream) {
  const float* x  = (const float*)d_in[0];
  const float* cb = (const float*)d_in[1];
  const int* p_start = (const int*)d_in[2];
  const int* p_end   = (const int*)d_in[3];

  float* ws = (float*)d_ws;
  float* sc      = ws;                                            // 8192 f
  float* partial = ws + N_E;                                      // 8192 f
  unsigned short* cbf  = (unsigned short*)(ws + 2 * N_E);         // 1MB
  unsigned int*   cand = (unsigned int*)(cbf + (size_t)N_E * EDIM); // 16.8MB

  float* out      = (float*)d_out;
  float* out_xq   = out;                 // 2097152
  float* out_loss = out + NELEM;         // 1
  float* out_idx  = out + NELEM + 1;     // 32768

  vq_sc<<<N_E / 256, 256, 0, stream>>>(cb, sc, cbf);
  dim3 g1(NTOK / TTOK, N_E / TCODE);
  vq_pass1<<<g1, 256, 0, stream>>>(x, cbf, cand, p_start, p_end);
  vq_rescue<<<NTOK / TOKB, 256, 0, stream>>>(x, cb, sc, cand, out_xq, out_idx,
                                             partial, p_start, p_end);
  vq_loss<<<1, 256, 0, stream>>>(partial, out_loss);
}